// Round 1
// baseline (2967.342 us; speedup 1.0000x reference)
//
#include <hip/hip_runtime.h>

#define BN 4096
#define BD 128
#define NB 4
#define TOPK 20

// ---------------- Projection: Q = xWq + bq, K = xWk + bk (f64 accumulate) ----------------
// block = 256 thr, 32 rows; tid<128 -> Q col e, tid>=128 -> K col e.
__global__ __launch_bounds__(256) void proj_kernel(
    const float* __restrict__ x,
    const float* __restrict__ Wq, const float* __restrict__ bq,
    const float* __restrict__ Wk, const float* __restrict__ bk,
    double* __restrict__ Qd, double* __restrict__ Kd) {
  __shared__ double xs[32][129];
  const int tid = threadIdx.x;
  const long row0 = (long)blockIdx.x * 32;
  const float* xsrc = x + row0 * BD;
  for (int i = tid; i < 32 * BD; i += 256) xs[i >> 7][i & 127] = (double)xsrc[i];
  __syncthreads();

  const int e = tid & 127;
  const bool isK = tid >= 128;
  const float* W = isK ? Wk : Wq;
  const float* bias = isK ? bk : bq;
  double* Od = isK ? Kd : Qd;

  double acc[32];
  const double binit = (double)bias[e];
#pragma unroll
  for (int r = 0; r < 32; ++r) acc[r] = binit;

  for (int d = 0; d < BD; ++d) {
    const double wv = (double)W[d * BD + e];
#pragma unroll
    for (int r = 0; r < 32; ++r) acc[r] = fma(xs[r][d], wv, acc[r]);
  }

  double* op = Od + row0 * BD + e;
#pragma unroll
  for (int r = 0; r < 32; ++r) op[(long)r * BD] = acc[r];
}

// ---------------- Fused scores + exact top-20 + sparse softmax + write ----------------
// block = 512 thr (8 waves) handles 16 rows of one batch b. grid = 4*256 = 1024.
// Phase 1: f64 dot products, raw f32 scores spilled into d_out (scratch until overwritten).
// Phase 2: exact top-20 per row (1 row per wave, x2), jax tie-break (value desc, index asc).
// Phase 3: constant fill; Phase 4: scatter 20 specials.
__global__ __launch_bounds__(512, 2) void attn_topk_kernel(
    const double* __restrict__ Qd, const double* __restrict__ Kd,
    float* __restrict__ out) {
  __shared__ double qsd[16][BD];
  __shared__ float lutval[16][TOPK];
  __shared__ int lutcol[16][TOPK];
  __shared__ float rowc0[16];

  const int tid = threadIdx.x;
  const int lane = tid & 63;
  const int w = tid >> 6;              // wave 0..7 = column group
  const int blk = blockIdx.x;
  const int b = blk >> 8;              // 256 blocks per batch
  const int row0 = (blk & 255) << 4;   // 16 rows per block

  // stage Q rows (f64)
  {
    const double* qsrc = Qd + ((long)b * BN + row0) * BD;
    double* qdst = &qsd[0][0];
    for (int i = tid; i < 16 * BD; i += 512) qdst[i] = qsrc[i];
  }
  __syncthreads();

  float* outrow = out + ((long)b * BN + row0) * BN;
  const double* kb = Kd + (long)b * BN * BD;
  const double rs = 8.8388347648318447e-02;  // 1/sqrt(128), applied in f64 then one f32 round

  // ---- Phase 1: scores ----
  for (int t = 0; t < 8; ++t) {
    const int col = t * 512 + w * 64 + lane;
    const double2* kc = (const double2*)(kb + (long)col * BD);
    double acc[16];
#pragma unroll
    for (int r = 0; r < 16; ++r) acc[r] = 0.0;
#pragma unroll
    for (int ph = 0; ph < 4; ++ph) {
      double2 kk[16];
#pragma unroll
      for (int j = 0; j < 16; ++j) kk[j] = kc[ph * 16 + j];
#pragma unroll
      for (int j = 0; j < 16; ++j) {
#pragma unroll
        for (int r = 0; r < 16; ++r) {
          const double2 qq = *(const double2*)&qsd[r][ph * 32 + j * 2];
          acc[r] = fma(qq.y, kk[j].y, fma(qq.x, kk[j].x, acc[r]));
        }
      }
    }
#pragma unroll
    for (int r = 0; r < 16; ++r)
      outrow[(long)r * BN + col] = (float)(acc[r] * rs);
  }
  __syncthreads();

  // ---- Phase 2: exact top-20 per row; wave w handles rows w and w+8 ----
  for (int rr = 0; rr < 2; ++rr) {
    const int r = w + rr * 8;
    const float* sp = outrow + (long)r * BN + lane;  // lane owns cols lane + 64*c
    float v[64];
#pragma unroll
    for (int c = 0; c < 64; ++c) v[c] = sp[c * 64];

    // per-lane top-2 (earliest col wins on ties)
    float m1 = v[0], m2 = -3.4e38f;
    int c1 = 0, c2 = 0;
#pragma unroll
    for (int c = 1; c < 64; ++c) {
      if (v[c] > m1) { m2 = m1; c2 = c1; m1 = v[c]; c1 = c; }
      else if (v[c] > m2) { m2 = v[c]; c2 = c; }
    }

    unsigned long long taken = 0ull;
    int s = 0;
    float cur = m1; int curlc = c1;
    float m = 0.0f, se = 0.0f;

    for (int it = 0; it < TOPK; ++it) {
      float rv = cur;
      int rc = lane + (curlc << 6);  // global col of candidate
      for (int off = 32; off; off >>= 1) {
        float ov = __shfl_xor(rv, off);
        int oc = __shfl_xor(rc, off);
        if (ov > rv || (ov == rv && oc < rc)) { rv = ov; rc = oc; }
      }
      // rv/rc = global winner (uniform)
      if (it == 0) m = fmaxf(rv, 0.0f);
      se += expf(rv - m);
      if (lane == 0) { lutval[r][it] = rv; lutcol[r][it] = rc; }
      if ((rc & 63) == lane) {
        taken |= 1ull << (rc >> 6);
        ++s;
        if (s == 1) { cur = m2; curlc = c2; }
        else {
          float bm = -3.4e38f; int bc = 0;
#pragma unroll
          for (int c = 0; c < 64; ++c) {
            const bool ok = !((taken >> c) & 1ull);
            if (ok && v[c] > bm) { bm = v[c]; bc = c; }
          }
          cur = bm; curlc = bc;
        }
      }
    }

    const float Z = se + (float)(BN - TOPK) * expf(-m);
    if (lane < TOPK) lutval[r][lane] = expf(lutval[r][lane] - m) / Z;
    if (lane == 0) rowc0[r] = expf(-m) / Z;
  }
  __syncthreads();

  // ---- Phase 3: constant fill (float4 streams) ----
  for (int r = 0; r < 16; ++r) {
    const float c0 = rowc0[r];
    const float4 cv = make_float4(c0, c0, c0, c0);
    float4* op = ((float4*)(outrow + (long)r * BN)) + w * 128 + lane * 2;
    op[0] = cv;
    op[1] = cv;
  }
  __syncthreads();

  // ---- Phase 4: scatter specials ----
  if (tid < 16 * TOPK) {
    const int r = tid / TOPK;
    const int k = tid % TOPK;
    outrow[(long)r * BN + lutcol[r][k]] = lutval[r][k];
  }
}

extern "C" void kernel_launch(void* const* d_in, const int* in_sizes, int n_in,
                              void* d_out, int out_size, void* d_ws, size_t ws_size,
                              hipStream_t stream) {
  const float* x  = (const float*)d_in[0];
  const float* Wq = (const float*)d_in[1];
  const float* bq = (const float*)d_in[2];
  const float* Wk = (const float*)d_in[3];
  const float* bk = (const float*)d_in[4];
  float* out = (float*)d_out;

  // f64 Q and K in workspace: 2 * 4*4096*128 * 8B = 32 MiB
  double* Qd = (double*)d_ws;
  double* Kd = Qd + (long)NB * BN * BD;

  proj_kernel<<<NB * BN / 32, 256, 0, stream>>>(x, Wq, bq, Wk, bk, Qd, Kd);
  attn_topk_kernel<<<NB * (BN / 16), 512, 0, stream>>>(Qd, Kd, out);
}

// Round 3
// 457.653 us; speedup vs baseline: 6.4838x; 6.4838x over previous
//
#include <hip/hip_runtime.h>

#define BN 4096
#define BD 128
#define NB 4
#define TOPK 20
#define CAND 128
#define EPS 0.06f

typedef float f32x4 __attribute__((ext_vector_type(4)));
typedef short bf16x8 __attribute__((ext_vector_type(8)));

__device__ inline unsigned short f2bf(float f) {
  unsigned int u = __float_as_uint(f);
  unsigned int r = (u + 0x7FFFu + ((u >> 16) & 1u)) >> 16;
  return (unsigned short)r;
}

// ---------------- Projection (f64 accumulate) -> Qd, Kd (f64) + Khi (bf16) ----------------
__global__ __launch_bounds__(256) void proj_kernel(
    const float* __restrict__ x,
    const float* __restrict__ Wq, const float* __restrict__ bq,
    const float* __restrict__ Wk, const float* __restrict__ bk,
    double* __restrict__ Qd, double* __restrict__ Kd, unsigned short* __restrict__ Khi) {
  __shared__ double xs[32][129];
  const int tid = threadIdx.x;
  const long row0 = (long)blockIdx.x * 32;
  const float* xsrc = x + row0 * BD;
  for (int i = tid; i < 32 * BD; i += 256) xs[i >> 7][i & 127] = (double)xsrc[i];
  __syncthreads();

  const int e = tid & 127;
  const bool isK = tid >= 128;
  const float* W = isK ? Wk : Wq;
  const float* bias = isK ? bk : bq;
  double* Od = isK ? Kd : Qd;

  double acc[32];
  const double binit = (double)bias[e];
#pragma unroll
  for (int r = 0; r < 32; ++r) acc[r] = binit;

  for (int d = 0; d < BD; ++d) {
    const double wv = (double)W[d * BD + e];
#pragma unroll
    for (int r = 0; r < 32; ++r) acc[r] = fma(xs[r][d], wv, acc[r]);
  }

#pragma unroll
  for (int r = 0; r < 32; ++r) {
    const double a = acc[r];
    const long o = (row0 + r) * BD + e;
    Od[o] = a;
    if (isK) Khi[o] = f2bf((float)a);
  }
}

// ---------------- Screen: bf16 MFMA scores + tau + candidate emit ----------------
// 1 wave per block; wave owns 32 q-rows. D = K_tile(16x32) * Q_tile(32x16).
// C layout: col(lane&15)=q-row, row((lane>>4)*4+reg)=kv-in-tile.
__device__ inline void ins5(float (&t)[5], float v) {
  if (v > t[4]) {
    t[4] = v;
#pragma unroll
    for (int i = 4; i > 0; --i) {
      if (t[i] > t[i - 1]) { float tmp = t[i - 1]; t[i - 1] = t[i]; t[i] = tmp; }
    }
  }
}

__global__ __launch_bounds__(64) void screen_kernel(
    const double* __restrict__ Qd, const unsigned short* __restrict__ Khi,
    unsigned short* __restrict__ cand, unsigned int* __restrict__ cnt) {
  const int lane = threadIdx.x;
  // XCD-affinity swizzle: xcd = blk%8 (dispatch heuristic); give each XCD one batch.
  const int blk = blockIdx.x;
  const int b = (blk & 7) >> 1;                    // 2 XCDs per batch
  const int i = ((blk >> 3) << 1) | (blk & 1);     // 0..127
  const int rowbase = i << 5;                      // 32 rows per block
  const int lq = lane & 15;
  const int gg = lane >> 4;
  const float RS = 0.088388347648318447f;

  // Q fragments for 2 row-tiles x 4 k-steps (from f64 Qd, one-time)
  bf16x8 bqf[2][4];
#pragma unroll
  for (int t2 = 0; t2 < 2; ++t2) {
    const double* qp = Qd + ((long)b * BN + rowbase + t2 * 16 + lq) * BD;
#pragma unroll
    for (int ks = 0; ks < 4; ++ks) {
      const int dbase = ks * 32 + gg * 8;
      bf16x8 pk;
#pragma unroll
      for (int j = 0; j < 8; ++j) pk[j] = (short)f2bf((float)qp[dbase + j]);
      bqf[t2][ks] = pk;
    }
  }

  const unsigned short* kb = Khi + (long)b * BN * BD;
  const long arow = (long)(lane & 15) * BD + gg * 8;  // A-frag offset within tile

  float t5a[5], t5b[5];
#pragma unroll
  for (int i2 = 0; i2 < 5; ++i2) { t5a[i2] = -3.4e38f; t5b[i2] = -3.4e38f; }

  // ---- pass 1: per-lane top-5 (values only), with A-frag prefetch ----
  bf16x8 a[4], an[4];
#pragma unroll
  for (int ks = 0; ks < 4; ++ks) a[ks] = *(const bf16x8*)(kb + arow + ks * 32);
  for (int t = 0; t < 256; ++t) {
    if (t < 255) {
      const unsigned short* nb = kb + (long)(t + 1) * 16 * BD + arow;
#pragma unroll
      for (int ks = 0; ks < 4; ++ks) an[ks] = *(const bf16x8*)(nb + ks * 32);
    }
    f32x4 acc0 = {0.f, 0.f, 0.f, 0.f}, acc1 = {0.f, 0.f, 0.f, 0.f};
#pragma unroll
    for (int ks = 0; ks < 4; ++ks) {
      acc0 = __builtin_amdgcn_mfma_f32_16x16x32_bf16(a[ks], bqf[0][ks], acc0, 0, 0, 0);
      acc1 = __builtin_amdgcn_mfma_f32_16x16x32_bf16(a[ks], bqf[1][ks], acc1, 0, 0, 0);
    }
#pragma unroll
    for (int reg = 0; reg < 4; ++reg) {
      ins5(t5a, acc0[reg] * RS);
      ins5(t5b, acc1[reg] * RS);
    }
#pragma unroll
    for (int ks = 0; ks < 4; ++ks) a[ks] = an[ks];
  }

  // tau = min over the row's 4 lanes of per-lane 5th-largest (lower bound on 20th)
  float ta = t5a[4], tb = t5b[4];
  ta = fminf(ta, __shfl_xor(ta, 16)); ta = fminf(ta, __shfl_xor(ta, 32));
  tb = fminf(tb, __shfl_xor(tb, 16)); tb = fminf(tb, __shfl_xor(tb, 32));
  const float tha = ta - EPS, thb = tb - EPS;

  __shared__ unsigned int scnt[32];
  __shared__ unsigned short slist[32][CAND];
  if (lane < 32) scnt[lane] = 0;
  __syncthreads();

  // ---- pass 2: identical MFMAs, emit candidates ----
#pragma unroll
  for (int ks = 0; ks < 4; ++ks) a[ks] = *(const bf16x8*)(kb + arow + ks * 32);
  for (int t = 0; t < 256; ++t) {
    if (t < 255) {
      const unsigned short* nb = kb + (long)(t + 1) * 16 * BD + arow;
#pragma unroll
      for (int ks = 0; ks < 4; ++ks) an[ks] = *(const bf16x8*)(nb + ks * 32);
    }
    f32x4 acc0 = {0.f, 0.f, 0.f, 0.f}, acc1 = {0.f, 0.f, 0.f, 0.f};
#pragma unroll
    for (int ks = 0; ks < 4; ++ks) {
      acc0 = __builtin_amdgcn_mfma_f32_16x16x32_bf16(a[ks], bqf[0][ks], acc0, 0, 0, 0);
      acc1 = __builtin_amdgcn_mfma_f32_16x16x32_bf16(a[ks], bqf[1][ks], acc1, 0, 0, 0);
    }
#pragma unroll
    for (int reg = 0; reg < 4; ++reg) {
      const float s0 = acc0[reg] * RS;
      if (s0 >= tha) {
        unsigned int p = atomicAdd(&scnt[lq], 1u);
        if (p < CAND) slist[lq][p] = (unsigned short)(t * 16 + gg * 4 + reg);
      }
      const float s1 = acc1[reg] * RS;
      if (s1 >= thb) {
        unsigned int p = atomicAdd(&scnt[16 + lq], 1u);
        if (p < CAND) slist[16 + lq][p] = (unsigned short)(t * 16 + gg * 4 + reg);
      }
    }
#pragma unroll
    for (int ks = 0; ks < 4; ++ks) a[ks] = an[ks];
  }
  __syncthreads();

  const long growbase = (long)b * BN + rowbase;
  if (lane < 32) cnt[growbase + lane] = min(scnt[lane], (unsigned int)CAND);
  const unsigned short* sl = &slist[0][0];
  for (int j = lane; j < 32 * CAND; j += 64) cand[growbase * CAND + j] = sl[j];
}

// ---------------- Finalize: exact f64 rescore (round-1 numerics) + top-20 + softmax + write ----------------
__device__ inline float rescore_f64(const double* __restrict__ kp, const double* __restrict__ q) {
  double acc = 0.0;
#pragma unroll
  for (int i = 0; i < 64; ++i) {
    acc = fma(q[2 * i], kp[2 * i], acc);
    acc = fma(q[2 * i + 1], kp[2 * i + 1], acc);
  }
  return (float)(acc * 8.8388347648318447e-02);
}

__global__ __launch_bounds__(512) void finalize_kernel(
    const double* __restrict__ Qd, const double* __restrict__ Kd,
    const unsigned short* __restrict__ cand, const unsigned int* __restrict__ cnt,
    float* __restrict__ out) {
  __shared__ double qsd[16][BD];
  __shared__ float lutval[16][TOPK];
  __shared__ int lutcol[16][TOPK];
  __shared__ float rowc0[16];

  const int tid = threadIdx.x;
  const int lane = tid & 63;
  const int w = tid >> 6;
  const int blk = blockIdx.x;
  const int b = blk >> 8;
  const int row0 = (blk & 255) << 4;

  {
    const double* qsrc = Qd + ((long)b * BN + row0) * BD;
    double* qdst = &qsd[0][0];
    for (int i = tid; i < 16 * BD; i += 512) qdst[i] = qsrc[i];
  }
  __syncthreads();

  float* outrow = out + ((long)b * BN + row0) * BN;
  const double* kb = Kd + (long)b * BN * BD;

  for (int rr = 0; rr < 2; ++rr) {
    const int r = w + rr * 8;
    const long grow = (long)b * BN + row0 + r;
    const int c = (int)min(cnt[grow], (unsigned int)CAND);

    // up to 2 candidates per lane, kept ordered by (value desc, col asc)
    int kv0 = 0x7fffffff, kv1 = 0x7fffffff;
    float v0 = -3.4e38f, v1 = -3.4e38f;
    if (lane < c) {
      kv0 = (int)cand[grow * CAND + lane];
      v0 = rescore_f64(kb + (long)kv0 * BD, &qsd[r][0]);
    }
    if (lane + 64 < c) {
      kv1 = (int)cand[grow * CAND + lane + 64];
      v1 = rescore_f64(kb + (long)kv1 * BD, &qsd[r][0]);
    }
    if (v1 > v0 || (v1 == v0 && kv1 < kv0)) {
      float tv = v0; v0 = v1; v1 = tv;
      int tk = kv0; kv0 = kv1; kv1 = tk;
    }

    float m = 0.0f, se = 0.0f;
    for (int it = 0; it < TOPK; ++it) {
      float rv = v0;
      int rc = kv0;
      for (int off = 32; off; off >>= 1) {
        const float ov = __shfl_xor(rv, off);
        const int oc = __shfl_xor(rc, off);
        if (ov > rv || (ov == rv && oc < rc)) { rv = ov; rc = oc; }
      }
      if (it == 0) m = fmaxf(rv, 0.0f);
      se += expf(rv - m);
      if (lane == 0) { lutval[r][it] = rv; lutcol[r][it] = rc; }
      if (kv0 == rc) { v0 = v1; kv0 = kv1; v1 = -3.4e38f; kv1 = 0x7fffffff; }
    }

    const float Z = se + (float)(BN - TOPK) * expf(-m);
    if (lane < TOPK) lutval[r][lane] = expf(lutval[r][lane] - m) / Z;
    if (lane == 0) rowc0[r] = expf(-m) / Z;
  }
  __syncthreads();

  // constant fill
  for (int r = 0; r < 16; ++r) {
    const float c0 = rowc0[r];
    const float4 cv = make_float4(c0, c0, c0, c0);
    float4* op = ((float4*)(outrow + (long)r * BN)) + w * 128 + lane * 2;
    op[0] = cv;
    op[1] = cv;
  }
  __syncthreads();

  // scatter specials
  if (tid < 16 * TOPK) {
    const int r = tid / TOPK;
    const int k = tid % TOPK;
    outrow[(long)r * BN + lutcol[r][k]] = lutval[r][k];
  }
}

extern "C" void kernel_launch(void* const* d_in, const int* in_sizes, int n_in,
                              void* d_out, int out_size, void* d_ws, size_t ws_size,
                              hipStream_t stream) {
  const float* x  = (const float*)d_in[0];
  const float* Wq = (const float*)d_in[1];
  const float* bq = (const float*)d_in[2];
  const float* Wk = (const float*)d_in[3];
  const float* bk = (const float*)d_in[4];
  float* out = (float*)d_out;

  const long NE = (long)NB * BN * BD;  // 2,097,152 elements
  double* Qd = (double*)d_ws;                          // 16 MB
  double* Kd = Qd + NE;                                // 16 MB
  unsigned short* Khi = (unsigned short*)(Kd + NE);    // 4 MB
  unsigned short* cand = Khi + NE;                     // 4 MB (NB*BN*CAND)
  unsigned int* cnt = (unsigned int*)(cand + (long)NB * BN * CAND);  // 64 KB

  proj_kernel<<<NB * BN / 32, 256, 0, stream>>>(x, Wq, bq, Wk, bk, Qd, Kd, Khi);
  screen_kernel<<<NB * (BN / 32), 64, 0, stream>>>(Qd, Khi, cand, cnt);
  finalize_kernel<<<NB * (BN / 16), 512, 0, stream>>>(Qd, Kd, cand, cnt, out);
}

// Round 4
// 321.820 us; speedup vs baseline: 9.2205x; 1.4221x over previous
//
#include <hip/hip_runtime.h>

#define BN 4096
#define BD 128
#define NB 4
#define TOPK 20
#define CAND 128
#define EPS 0.06f

typedef float f32x4 __attribute__((ext_vector_type(4)));
typedef short bf16x8 __attribute__((ext_vector_type(8)));

__device__ inline unsigned short f2bf(float f) {
  unsigned int u = __float_as_uint(f);
  unsigned int r = (u + 0x7FFFu + ((u >> 16) & 1u)) >> 16;
  return (unsigned short)r;
}

// ---------------- Projection (f64 accumulate) -> Qd, Kd (f64) + Khi (bf16) ----------------
__global__ __launch_bounds__(256) void proj_kernel(
    const float* __restrict__ x,
    const float* __restrict__ Wq, const float* __restrict__ bq,
    const float* __restrict__ Wk, const float* __restrict__ bk,
    double* __restrict__ Qd, double* __restrict__ Kd, unsigned short* __restrict__ Khi) {
  __shared__ double xs[32][129];
  const int tid = threadIdx.x;
  const long row0 = (long)blockIdx.x * 32;
  const float* xsrc = x + row0 * BD;
  for (int i = tid; i < 32 * BD; i += 256) xs[i >> 7][i & 127] = (double)xsrc[i];
  __syncthreads();

  const int e = tid & 127;
  const bool isK = tid >= 128;
  const float* W = isK ? Wk : Wq;
  const float* bias = isK ? bk : bq;
  double* Od = isK ? Kd : Qd;

  double acc[32];
  const double binit = (double)bias[e];
#pragma unroll
  for (int r = 0; r < 32; ++r) acc[r] = binit;

  for (int d = 0; d < BD; ++d) {
    const double wv = (double)W[d * BD + e];
#pragma unroll
    for (int r = 0; r < 32; ++r) acc[r] = fma(xs[r][d], wv, acc[r]);
  }

#pragma unroll
  for (int r = 0; r < 32; ++r) {
    const double a = acc[r];
    const long o = (row0 + r) * BD + e;
    Od[o] = a;
    if (isK) Khi[o] = f2bf((float)a);
  }
}

// ---------------- Screen: bf16 MFMA + pooled-exact tau + candidate emit ----------------
// Block = 8 waves (512 thr) covering 32 q-rows; wave w handles t-eighth [w*32, w*32+32).
// Per wave: rows via 2 row-tiles (lq = lane&15), kv-in-tile via gg=lane>>4 and reg.
// tau per row = 20th largest of pooled per-lane top-2 (64 values) via bitonic sort.
__global__ __launch_bounds__(512) void screen_kernel(
    const double* __restrict__ Qd, const unsigned short* __restrict__ Khi,
    unsigned short* __restrict__ cand, unsigned int* __restrict__ cnt) {
  const int tid = threadIdx.x;
  const int lane = tid & 63;
  const int w = tid >> 6;                  // t-eighth
  const int blk = blockIdx.x;
  const int b = (blk & 7) >> 1;            // 2 XCDs per batch
  const int i = ((blk >> 3) << 1) | (blk & 1);   // 0..127
  const int rowbase = i << 5;              // 32 rows per block
  const int lq = lane & 15;
  const int gg = lane >> 4;
  const float RS = 0.088388347648318447f;

  __shared__ float pool[32][64];
  __shared__ float tauLds[32];
  __shared__ unsigned int scnt[32];
  __shared__ unsigned short slist[32][CAND];

  // Q fragments for 2 row-tiles x 4 k-steps (from f64 Qd, one-time)
  bf16x8 bqf[2][4];
#pragma unroll
  for (int t2 = 0; t2 < 2; ++t2) {
    const double* qp = Qd + ((long)b * BN + rowbase + t2 * 16 + lq) * BD;
#pragma unroll
    for (int ks = 0; ks < 4; ++ks) {
      const int dbase = ks * 32 + gg * 8;
      bf16x8 pk;
#pragma unroll
      for (int j = 0; j < 8; ++j) pk[j] = (short)f2bf((float)qp[dbase + j]);
      bqf[t2][ks] = pk;
    }
  }

  const unsigned short* kb = Khi + (long)b * BN * BD;
  const long arow = (long)lq * BD + gg * 8;  // A-frag offset within tile
  const int t0 = w * 32;
  const unsigned short* tb0 = kb + (long)t0 * 16 * BD + arow;

  // ---- pass 1: per-lane top-2 ----
  float t1a = -3.4e38f, t2a = -3.4e38f, t1b = -3.4e38f, t2b = -3.4e38f;
  bf16x8 a[4], an[4];
#pragma unroll
  for (int ks = 0; ks < 4; ++ks) a[ks] = *(const bf16x8*)(tb0 + ks * 32);
  for (int tt = 0; tt < 32; ++tt) {
    if (tt < 31) {
      const unsigned short* nb = kb + (long)(t0 + tt + 1) * 16 * BD + arow;
#pragma unroll
      for (int ks = 0; ks < 4; ++ks) an[ks] = *(const bf16x8*)(nb + ks * 32);
    }
    f32x4 acc0 = {0.f, 0.f, 0.f, 0.f}, acc1 = {0.f, 0.f, 0.f, 0.f};
#pragma unroll
    for (int ks = 0; ks < 4; ++ks) {
      acc0 = __builtin_amdgcn_mfma_f32_16x16x32_bf16(a[ks], bqf[0][ks], acc0, 0, 0, 0);
      acc1 = __builtin_amdgcn_mfma_f32_16x16x32_bf16(a[ks], bqf[1][ks], acc1, 0, 0, 0);
    }
#pragma unroll
    for (int reg = 0; reg < 4; ++reg) {
      const float s0 = acc0[reg] * RS;
      const float m1a = fmaxf(t1a, s0);
      t2a = fmaxf(t2a, fminf(t1a, s0));
      t1a = m1a;
      const float s1 = acc1[reg] * RS;
      const float m1b = fmaxf(t1b, s1);
      t2b = fmaxf(t2b, fminf(t1b, s1));
      t1b = m1b;
    }
#pragma unroll
    for (int ks = 0; ks < 4; ++ks) a[ks] = an[ks];
  }

  // pool per-lane top-2: slot = w*8 + gg*2 + {0,1}
  pool[lq][w * 8 + gg * 2 + 0] = t1a;
  pool[lq][w * 8 + gg * 2 + 1] = t2a;
  pool[16 + lq][w * 8 + gg * 2 + 0] = t1b;
  pool[16 + lq][w * 8 + gg * 2 + 1] = t2b;
  if (tid < 32) scnt[tid] = 0;
  __syncthreads();

  // ---- tau: bitonic-64 ascending per row; 20th largest at index 44 ----
  for (int rr = 0; rr < 4; ++rr) {
    const int r = w * 4 + rr;
    float v = pool[r][lane];
#pragma unroll
    for (int k = 2; k <= 64; k <<= 1) {
#pragma unroll
      for (int j = k >> 1; j > 0; j >>= 1) {
        const float o = __shfl_xor(v, j);
        const bool keepmin = (((lane & k) == 0) == ((lane & j) == 0));
        v = keepmin ? fminf(v, o) : fmaxf(v, o);
      }
    }
    const float tau = __shfl(v, 44);
    if (lane == 0) tauLds[r] = tau;
  }
  __syncthreads();

  const float tha = tauLds[lq] - EPS;
  const float thb = tauLds[16 + lq] - EPS;

  // ---- pass 2: identical MFMAs, emit candidates ----
#pragma unroll
  for (int ks = 0; ks < 4; ++ks) a[ks] = *(const bf16x8*)(tb0 + ks * 32);
  for (int tt = 0; tt < 32; ++tt) {
    if (tt < 31) {
      const unsigned short* nb = kb + (long)(t0 + tt + 1) * 16 * BD + arow;
#pragma unroll
      for (int ks = 0; ks < 4; ++ks) an[ks] = *(const bf16x8*)(nb + ks * 32);
    }
    f32x4 acc0 = {0.f, 0.f, 0.f, 0.f}, acc1 = {0.f, 0.f, 0.f, 0.f};
#pragma unroll
    for (int ks = 0; ks < 4; ++ks) {
      acc0 = __builtin_amdgcn_mfma_f32_16x16x32_bf16(a[ks], bqf[0][ks], acc0, 0, 0, 0);
      acc1 = __builtin_amdgcn_mfma_f32_16x16x32_bf16(a[ks], bqf[1][ks], acc1, 0, 0, 0);
    }
#pragma unroll
    for (int reg = 0; reg < 4; ++reg) {
      const int col = (t0 + tt) * 16 + gg * 4 + reg;
      const float s0 = acc0[reg] * RS;
      if (s0 >= tha) {
        unsigned int p = atomicAdd(&scnt[lq], 1u);
        if (p < CAND) slist[lq][p] = (unsigned short)col;
      }
      const float s1 = acc1[reg] * RS;
      if (s1 >= thb) {
        unsigned int p = atomicAdd(&scnt[16 + lq], 1u);
        if (p < CAND) slist[16 + lq][p] = (unsigned short)col;
      }
    }
#pragma unroll
    for (int ks = 0; ks < 4; ++ks) a[ks] = an[ks];
  }
  __syncthreads();

  const long growbase = (long)b * BN + rowbase;
  if (tid < 32) cnt[growbase + tid] = min(scnt[tid], (unsigned int)CAND);
  const unsigned short* sl = &slist[0][0];
  for (int j = tid; j < 32 * CAND; j += 512) cand[growbase * CAND + j] = sl[j];
}

// ---------------- Finalize: exact f64 rescore + top-20 + softmax + write ----------------
__device__ inline float rescore_f64(const double2* __restrict__ kp2, const double2* __restrict__ q2) {
  double a0 = 0.0, a1 = 0.0, a2 = 0.0, a3 = 0.0;
#pragma unroll
  for (int i = 0; i < 64; i += 4) {
    a0 = fma(q2[i + 0].y, kp2[i + 0].y, fma(q2[i + 0].x, kp2[i + 0].x, a0));
    a1 = fma(q2[i + 1].y, kp2[i + 1].y, fma(q2[i + 1].x, kp2[i + 1].x, a1));
    a2 = fma(q2[i + 2].y, kp2[i + 2].y, fma(q2[i + 2].x, kp2[i + 2].x, a2));
    a3 = fma(q2[i + 3].y, kp2[i + 3].y, fma(q2[i + 3].x, kp2[i + 3].x, a3));
  }
  return (float)(((a0 + a1) + (a2 + a3)) * 8.8388347648318447e-02);
}

__global__ __launch_bounds__(512) void finalize_kernel(
    const double* __restrict__ Qd, const double* __restrict__ Kd,
    const unsigned short* __restrict__ cand, const unsigned int* __restrict__ cnt,
    float* __restrict__ out) {
  __shared__ double qsd[16][BD];
  __shared__ float lutval[16][TOPK];
  __shared__ int lutcol[16][TOPK];
  __shared__ float rowc0[16];

  const int tid = threadIdx.x;
  const int lane = tid & 63;
  const int w = tid >> 6;
  const int blk = blockIdx.x;
  const int b = blk >> 8;
  const int row0 = (blk & 255) << 4;

  {
    const double* qsrc = Qd + ((long)b * BN + row0) * BD;
    double* qdst = &qsd[0][0];
    for (int i = tid; i < 16 * BD; i += 512) qdst[i] = qsrc[i];
  }
  __syncthreads();

  float* outrow = out + ((long)b * BN + row0) * BN;
  const double* kb = Kd + (long)b * BN * BD;

  for (int rr = 0; rr < 2; ++rr) {
    const int r = w + rr * 8;
    const long grow = (long)b * BN + row0 + r;
    const int c = (int)min(cnt[grow], (unsigned int)CAND);

    // up to 2 candidates per lane, kept ordered by (value desc, col asc)
    int kv0 = 0x7fffffff, kv1 = 0x7fffffff;
    float v0 = -3.4e38f, v1 = -3.4e38f;
    if (lane < c) {
      kv0 = (int)cand[grow * CAND + lane];
      v0 = rescore_f64((const double2*)(kb + (long)kv0 * BD), (const double2*)&qsd[r][0]);
    }
    if (lane + 64 < c) {
      kv1 = (int)cand[grow * CAND + lane + 64];
      v1 = rescore_f64((const double2*)(kb + (long)kv1 * BD), (const double2*)&qsd[r][0]);
    }
    if (v1 > v0 || (v1 == v0 && kv1 < kv0)) {
      float tv = v0; v0 = v1; v1 = tv;
      int tk = kv0; kv0 = kv1; kv1 = tk;
    }

    float m = 0.0f, se = 0.0f;
    for (int it = 0; it < TOPK; ++it) {
      float rv = v0;
      int rc = kv0;
      for (int off = 32; off; off >>= 1) {
        const float ov = __shfl_xor(rv, off);
        const int oc = __shfl_xor(rc, off);
        if (ov > rv || (ov == rv && oc < rc)) { rv = ov; rc = oc; }
      }
      if (it == 0) m = fmaxf(rv, 0.0f);
      se += expf(rv - m);
      if (lane == 0) { lutval[r][it] = rv; lutcol[r][it] = rc; }
      if (kv0 == rc) { v0 = v1; kv0 = kv1; v1 = -3.4e38f; kv1 = 0x7fffffff; }
    }

    const float Z = se + (float)(BN - TOPK) * expf(-m);
    if (lane < TOPK) lutval[r][lane] = expf(lutval[r][lane] - m) / Z;
    if (lane == 0) rowc0[r] = expf(-m) / Z;
  }
  __syncthreads();

  // constant fill
  for (int r = 0; r < 16; ++r) {
    const float c0 = rowc0[r];
    const float4 cv = make_float4(c0, c0, c0, c0);
    float4* op = ((float4*)(outrow + (long)r * BN)) + w * 128 + lane * 2;
    op[0] = cv;
    op[1] = cv;
  }
  __syncthreads();

  // scatter specials
  if (tid < 16 * TOPK) {
    const int r = tid / TOPK;
    const int k = tid % TOPK;
    outrow[(long)r * BN + lutcol[r][k]] = lutval[r][k];
  }
}

extern "C" void kernel_launch(void* const* d_in, const int* in_sizes, int n_in,
                              void* d_out, int out_size, void* d_ws, size_t ws_size,
                              hipStream_t stream) {
  const float* x  = (const float*)d_in[0];
  const float* Wq = (const float*)d_in[1];
  const float* bq = (const float*)d_in[2];
  const float* Wk = (const float*)d_in[3];
  const float* bk = (const float*)d_in[4];
  float* out = (float*)d_out;

  const long NE = (long)NB * BN * BD;  // 2,097,152 elements
  double* Qd = (double*)d_ws;                          // 16 MB
  double* Kd = Qd + NE;                                // 16 MB
  unsigned short* Khi = (unsigned short*)(Kd + NE);    // 4 MB
  unsigned short* cand = Khi + NE;                     // 4 MB (NB*BN*CAND)
  unsigned int* cnt = (unsigned int*)(cand + (long)NB * BN * CAND);  // 64 KB

  proj_kernel<<<NB * BN / 32, 256, 0, stream>>>(x, Wq, bq, Wk, bk, Qd, Kd, Khi);
  screen_kernel<<<NB * (BN / 32), 512, 0, stream>>>(Qd, Khi, cand, cnt);
  finalize_kernel<<<NB * (BN / 16), 512, 0, stream>>>(Qd, Kd, cand, cnt, out);
}